// Round 2
// baseline (11334.319 us; speedup 1.0000x reference)
//
#include <hip/hip_runtime.h>
#include <math.h>

__device__ __forceinline__ float sigf(float x){ return 1.f/(1.f+expf(-x)); }

// ---------------- zero fill ----------------
__global__ void zero_k(float* __restrict__ p, long n){
  long i = (long)blockIdx.x*blockDim.x + threadIdx.x;
  long stride = (long)gridDim.x*blockDim.x;
  for (; i<n; i+=stride) p[i] = 0.f;
}

// ---------------- emb[b][d] = lang_embeds[ li[li[b]] ][d] ----------------
__global__ void emb_k(const int* __restrict__ li, const float* __restrict__ le, float* __restrict__ emb){
  int b = blockIdx.x, d = threadIdx.x;
  int idx = li[li[b]];
  emb[b*64+d] = le[idx*64+d];
}

// ---------------- out[b][s][0:D1]=seq, [D1:D1+D2]=emb[b] ----------------
__global__ void build_concat_k(const float* __restrict__ seq, const float* __restrict__ emb,
                               float* __restrict__ out, int S, int D1, int D2, long total){
  long i = (long)blockIdx.x*blockDim.x + threadIdx.x;
  if (i>=total) return;
  int D = D1+D2;
  int d = (int)(i % D);
  long bs = i / D;
  int s = (int)(bs % S);
  int b = (int)(bs / S);
  out[i] = (d<D1) ? seq[((long)b*S+s)*D1 + d] : emb[b*64 + (d-D1)];
}

// ------- fp32 GEMM (B transposed): C[M,N] = A[M,K] @ W[N,K]^T (+bias)(+D)(+=C) -------
__global__ __launch_bounds__(256) void gemm_bt_k(
    const float* __restrict__ A, const float* __restrict__ W, float* __restrict__ C,
    const float* __restrict__ bias, const float* __restrict__ D, int ldd,
    int M, int N, int K, int lda, int ldb, int ldc, int accflag)
{
  __shared__ float As[16][68];
  __shared__ float Ws[16][68];
  int bm = blockIdx.y*64, bn = blockIdx.x*64;
  int tid = threadIdx.x;
  int tr = tid>>4, tc = tid&15;
  float acc[4][4] = {};
  for (int k0=0;k0<K;k0+=16){
    #pragma unroll
    for (int i=0;i<4;i++){
      int idx = tid + i*256;
      int r = idx>>4, c = idx&15;           // c consecutive with tid -> coalesced A row read
      float v = 0.f;
      if (bm+r<M && k0+c<K) v = A[(long)(bm+r)*lda + k0+c];
      As[c][r] = v;
    }
    #pragma unroll
    for (int i=0;i<4;i++){
      int idx = tid + i*256;
      int n = idx>>4, k = idx&15;           // k consecutive with tid -> coalesced W row read
      float v = 0.f;
      if (bn+n<N && k0+k<K) v = W[(long)(bn+n)*ldb + k0+k];
      Ws[k][n] = v;
    }
    __syncthreads();
    #pragma unroll
    for (int kk=0;kk<16;kk++){
      float4 av = *(const float4*)&As[kk][tr*4];
      float4 bv = *(const float4*)&Ws[kk][tc*4];
      float a0[4] = {av.x, av.y, av.z, av.w};
      float b0[4] = {bv.x, bv.y, bv.z, bv.w};
      #pragma unroll
      for (int i=0;i<4;i++)
        #pragma unroll
        for (int j=0;j<4;j++)
          acc[i][j] += a0[i]*b0[j];
    }
    __syncthreads();
  }
  #pragma unroll
  for (int i=0;i<4;i++){
    int r = bm + tr*4 + i;
    if (r>=M) continue;
    #pragma unroll
    for (int j=0;j<4;j++){
      int n = bn + tc*4 + j;
      if (n>=N) continue;
      float v = acc[i][j];
      if (bias) v += bias[n];
      if (D)    v += D[(long)r*ldd + n];
      if (accflag) v += C[(long)r*ldc + n];
      C[(long)r*ldc + n] = v;
    }
  }
}

// ---------------- LSTM pointwise: gates -> h,c (+ write into sequence buffer) ----------------
__global__ void lstm_act_k(const float* __restrict__ g, float* __restrict__ c, float* __restrict__ h,
                           float* __restrict__ seq_out, int H, int ldstate, int outld){
  int j = blockIdx.x*blockDim.x + threadIdx.x;
  int b = blockIdx.y;
  if (j>=H) return;
  const float* gr = g + (long)b*4*H;
  float gi = gr[j], gf = gr[H+j], gg = gr[2*H+j], go = gr[3*H+j];
  float cp = c[(long)b*ldstate + j];
  float cn = sigf(gf)*cp + sigf(gi)*tanhf(gg);
  float hn = sigf(go)*tanhf(cn);
  c[(long)b*ldstate + j] = cn;
  h[(long)b*ldstate + j] = hn;
  if (seq_out) seq_out[(long)b*outld + j] = hn;
}

// ------- scores[b][q][k] (+)= scale * dot(qh[q,b,0:256], kh[k,b,0:256]) -------
template<int LK>
__global__ __launch_bounds__(256) void attn_scores_k(const float* __restrict__ qh, const float* __restrict__ kh,
                                                     float* __restrict__ sc, float scale, int accf){
  __shared__ float Qs[48][65];
  __shared__ float Ks[LK][65];
  int b = blockIdx.x, tid = threadIdx.x;
  constexpr int NOUT = 48*LK;
  constexpr int NC = (NOUT + 255)/256;
  float acc[NC] = {};
  for (int e0=0;e0<256;e0+=64){
    for (int i=tid;i<48*64;i+=256){ int q=i>>6, e=i&63; Qs[q][e] = qh[((long)(q*512)+b)*256 + e0+e]; }
    for (int i=tid;i<LK*64;i+=256){ int k=i>>6, e=i&63; Ks[k][e] = kh[((long)(k*512)+b)*256 + e0+e]; }
    __syncthreads();
    #pragma unroll
    for (int c=0;c<NC;c++){
      int oi = tid + c*256;
      if (oi < NOUT){
        int q = oi / LK, k = oi % LK;
        float s = 0.f;
        #pragma unroll 8
        for (int e=0;e<64;e++) s += Qs[q][e]*Ks[k][e];
        acc[c] += s;
      }
    }
    __syncthreads();
  }
  #pragma unroll
  for (int c=0;c<NC;c++){
    int oi = tid + c*256;
    if (oi < NOUT){
      int q = oi / LK, k = oi % LK;
      long idx = ((long)b*48 + q)*LK + k;
      float v = acc[c]*scale;
      if (accf) v += sc[idx];
      sc[idx] = v;
    }
  }
}

// ---------------- row softmax (L small) ----------------
__global__ void softmax_rows_k(float* __restrict__ sc, int rows, int L){
  int r = blockIdx.x*blockDim.x + threadIdx.x;
  if (r>=rows) return;
  float* p = sc + (long)r*L;
  float m = -1e30f;
  for (int l=0;l<L;l++) m = fmaxf(m, p[l]);
  float s = 0.f;
  for (int l=0;l<L;l++){ float e = expf(p[l]-m); p[l]=e; s+=e; }
  float inv = 1.f/s;
  for (int l=0;l<L;l++) p[l]*=inv;
}

// ------- o[q][b][e-half] = sum_k attn[b][q][k]*vh[k][b][e]; o pre-offset, row stride 512 -------
template<int LK>
__global__ __launch_bounds__(256) void attn_av_k(const float* __restrict__ at, const float* __restrict__ vh,
                                                 float* __restrict__ o){
  __shared__ float As[48][LK+1];
  int b = blockIdx.x;
  int e = threadIdx.x;            // 256 cols per pass
  for (int i=threadIdx.x;i<48*LK;i+=256){ int q=i/LK, k=i%LK; As[q][k] = at[((long)b*48+q)*LK + k]; }
  __syncthreads();
  float acc[48];
  #pragma unroll
  for (int q=0;q<48;q++) acc[q]=0.f;
  for (int k=0;k<LK;k++){
    float v = vh[((long)(k*512)+b)*256 + e];
    #pragma unroll
    for (int q=0;q<48;q++) acc[q] += As[q][k]*v;
  }
  #pragma unroll
  for (int q=0;q<48;q++) o[((long)(q*512)+b)*512 + e] = acc[q];
}

// ------- exact 1.5-entmax via bisection; logits row (t,b) -> out[b][t][:] -------
__global__ void entmax_k(const float* __restrict__ logits, float* __restrict__ out){
  int wid = (blockIdx.x*blockDim.x + threadIdx.x)>>6;
  int lane = threadIdx.x & 63;
  if (wid >= 24576) return;
  const float* x = logits + (long)wid*128;
  float a = x[lane]*0.5f;
  float b2 = x[lane+64]*0.5f;
  float m = fmaxf(a,b2);
  #pragma unroll
  for (int off=32;off;off>>=1) m = fmaxf(m, __shfl_xor(m, off));
  a -= m; b2 -= m;
  float lo = -1.f, hi = 0.f;
  for (int it=0; it<32; ++it){
    float mid = 0.5f*(lo+hi);
    float va = fmaxf(a-mid,0.f), vb = fmaxf(b2-mid,0.f);
    float s = va*va + vb*vb;
    #pragma unroll
    for (int off=32;off;off>>=1) s += __shfl_xor(s, off);
    if (s >= 1.f) lo = mid; else hi = mid;
  }
  float tau = 0.5f*(lo+hi);
  int t = wid >> 9;
  int b = wid & 511;
  float* o = out + ((long)b*48 + t)*128;
  float va = fmaxf(a-tau,0.f), vb = fmaxf(b2-tau,0.f);
  o[lane] = va*va;
  o[lane+64] = vb*vb;
}

extern "C" void kernel_launch(void* const* d_in, const int* in_sizes, int n_in,
                              void* d_out, int out_size, void* d_ws, size_t ws_size,
                              hipStream_t stream) {
  const int*   li        = (const int*)  d_in[0];
  const float* char_seq  = (const float*)d_in[1];
  const float* tagset    = (const float*)d_in[2];
  const float* labels    = (const float*)d_in[3];
  const float* lang_emb  = (const float*)d_in[4];
  const float* c_wih_f   = (const float*)d_in[5];
  const float* c_whh_f   = (const float*)d_in[6];
  const float* c_b_f     = (const float*)d_in[7];
  const float* c_wih_b   = (const float*)d_in[8];
  const float* c_whh_b   = (const float*)d_in[9];
  const float* c_b_b     = (const float*)d_in[10];
  const float* t_wih_f   = (const float*)d_in[11];
  const float* t_whh_f   = (const float*)d_in[12];
  const float* t_b_f     = (const float*)d_in[13];
  const float* t_wih_b   = (const float*)d_in[14];
  const float* t_whh_b   = (const float*)d_in[15];
  const float* t_b_b     = (const float*)d_in[16];
  const float* cell_wih  = (const float*)d_in[17];
  const float* cell_whh  = (const float*)d_in[18];
  const float* cell_b    = (const float*)d_in[19];
  const float* c_in_w    = (const float*)d_in[20];
  const float* c_in_b    = (const float*)d_in[21];
  const float* c_out_w   = (const float*)d_in[22];
  const float* c_out_b   = (const float*)d_in[23];
  const float* t_in_w    = (const float*)d_in[24];
  const float* t_in_b    = (const float*)d_in[25];
  const float* t_out_w   = (const float*)d_in[26];
  const float* t_out_b   = (const float*)d_in[27];
  const float* fc_w      = (const float*)d_in[28];
  const float* fc_b      = (const float*)d_in[29];
  (void)n_in; (void)in_sizes; (void)out_size;

  float* w = (float*)d_ws;
  long off = 0;
  auto alloc = [&](long n){ float* p = w + off; off += n; return p; };
  float* emb      = alloc(32768);
  float* char_out = alloc(12582912);   // [48,512,512] rows (t,b)
  float* tag_out  = alloc(4194304);    // [16,512,512]
  float* hs       = alloc(12582912);   // [48,512,512]
  float* dec_h    = alloc(262144);     // [512,512]
  float* dec_c    = alloc(262144);
  float* hb       = alloc(131072);     // [512,256]
  float* cb       = alloc(131072);
  float* g        = alloc(1048576);    // [512,2048]
  float* arena    = alloc(29884416);
  long needed_bytes = off * 4;
  if ((long)ws_size < needed_bytes) {
    // workspace too small: leave a clean numeric failure instead of a fault
    hipLaunchKernelGGL(zero_k, dim3(64), dim3(256), 0, stream, (float*)d_out, (long)128);
    return;
  }

  // arena overlays (phases strictly sequential)
  float* cs   = arena;                  // char phase: 4,718,592
  float* cxg  = arena + 4718592l;       // 25,165,824 (fwd then bwd)
  float* ts   = arena;                  // tag phase: 1,048,576
  float* txg  = arena + 1048576l;       // 8,388,608
  float* o_pv = arena;                  // attn phase: 12,582,912
  float* qh_h = arena + 12582912l;      // 6,291,456
  float* kh_h = arena + 18874368l;      // 6,291,456
  float* vh_h = qh_h;                   // reuse after scores
  float* ca   = arena + 12582912l;      // 12,582,912 (over qh_h+kh_h, after PV)
  float* sc_s = arena + 25165824l;      // 1,179,648
  float* logits = arena + 26345472l;    // 3,145,728 (written in attn phase, read by entmax)

  auto GEMM = [&](const float* A, const float* W2, float* C, const float* bias,
                  const float* D, int ldd, int M,int N,int K,int lda,int ldb,int ldc,int accf){
    dim3 gr((N+63)/64, (M+63)/64);
    hipLaunchKernelGGL(gemm_bt_k, gr, dim3(256), 0, stream, A,W2,C,bias,D,ldd,M,N,K,lda,ldb,ldc,accf);
  };

  // ---- emb ----
  hipLaunchKernelGGL(emb_k, dim3(512), dim3(64), 0, stream, li, lang_emb, emb);

  // ---- zero states (dec_h,dec_c,hb,cb contiguous) ----
  hipLaunchKernelGGL(zero_k, dim3(512), dim3(256), 0, stream, dec_h, (long)(262144+262144+131072+131072));

  // ---- char phase ----
  {
    long tot = 512l*48*192;
    hipLaunchKernelGGL(build_concat_k, dim3((unsigned)((tot+255)/256)), dim3(256), 0, stream,
                       char_seq, emb, cs, 48, 128, 64, tot);
  }
  GEMM(cs, c_wih_f, cxg, c_b_f, nullptr,0, 24576,1024,192, 192,192,1024, 0);
  for (int t=0;t<48;t++){
    GEMM(dec_h, c_whh_f, g, nullptr, cxg + (long)t*1024, 48*1024, 512,1024,256, 512,256,1024, 0);
    hipLaunchKernelGGL(lstm_act_k, dim3(1,512), dim3(256), 0, stream,
                       g, dec_c, dec_h, char_out + (long)t*262144, 256, 512, 512);
  }
  GEMM(cs, c_wih_b, cxg, c_b_b, nullptr,0, 24576,1024,192, 192,192,1024, 0);
  for (int t=0;t<48;t++){
    GEMM(hb, c_whh_b, g, nullptr, cxg + (long)(47-t)*1024, 48*1024, 512,1024,256, 256,256,1024, 0);
    hipLaunchKernelGGL(lstm_act_k, dim3(1,512), dim3(256), 0, stream,
                       g, cb, hb, char_out + (long)(47-t)*262144 + 256, 256, 256, 512);
  }

  // ---- tag phase ----
  {
    long tot = 512l*16*128;
    hipLaunchKernelGGL(build_concat_k, dim3((unsigned)((tot+255)/256)), dim3(256), 0, stream,
                       tagset, emb, ts, 16, 64, 64, tot);
  }
  GEMM(ts, t_wih_f, txg, t_b_f, nullptr,0, 8192,1024,128, 128,128,1024, 0);
  for (int t=0;t<16;t++){
    GEMM(dec_h+256, t_whh_f, g, nullptr, txg + (long)t*1024, 16*1024, 512,1024,256, 512,256,1024, 0);
    hipLaunchKernelGGL(lstm_act_k, dim3(1,512), dim3(256), 0, stream,
                       g, dec_c+256, dec_h+256, tag_out + (long)t*262144, 256, 512, 512);
  }
  hipLaunchKernelGGL(zero_k, dim3(256), dim3(256), 0, stream, hb, (long)262144);
  GEMM(ts, t_wih_b, txg, t_b_b, nullptr,0, 8192,1024,128, 128,128,1024, 0);
  for (int t=0;t<16;t++){
    GEMM(hb, t_whh_b, g, nullptr, txg + (long)(15-t)*1024, 16*1024, 512,1024,256, 256,256,1024, 0);
    hipLaunchKernelGGL(lstm_act_k, dim3(1,512), dim3(256), 0, stream,
                       g, cb, hb, tag_out + (long)(15-t)*262144 + 256, 256, 256, 512);
  }

  // ---- decoder (h0/c0 already in dec_h/dec_c) ----
  for (int t=0;t<48;t++){
    if (t==0){
      GEMM(dec_h, cell_whh, g, cell_b, nullptr,0, 512,2048,512, 512,512,2048, 0);
    } else {
      GEMM(labels + (long)t*128, cell_wih, g, cell_b, nullptr,0, 512,2048,128, 48*128,128,2048, 0);
      GEMM(dec_h, cell_whh, g, nullptr, nullptr,0, 512,2048,512, 512,512,2048, 1);
    }
    hipLaunchKernelGGL(lstm_act_k, dim3(2,512), dim3(256), 0, stream,
                       g, dec_c, dec_h, hs + (long)t*262144, 512, 512, 512);
  }

  const float scale = 0.044194173824159216f; // 1/sqrt(512)

  // ---- attentions (char: LK=48 src=char_out M=24576; tag: LK=16 src=tag_out M=8192) ----
  for (int which=0; which<2; ++which){
    const float* in_w  = which ? t_in_w  : c_in_w;
    const float* in_b  = which ? t_in_b  : c_in_b;
    const float* out_w = which ? t_out_w : c_out_w;
    const float* out_b = which ? t_out_b : c_out_b;
    const float* src   = which ? tag_out : char_out;
    int Mkv = which ? 8192 : 24576;
    int LK  = which ? 16 : 48;
    for (int p=0;p<2;p++){
      GEMM(hs,  in_w + (long)p*256*512,        qh_h, in_b + p*256,      nullptr,0, 24576,256,512, 512,512,256, 0);
      GEMM(src, in_w + (long)(512+p*256)*512,  kh_h, in_b + 512+p*256,  nullptr,0, Mkv,  256,512, 512,512,256, 0);
      if (LK==48) hipLaunchKernelGGL((attn_scores_k<48>), dim3(512), dim3(256), 0, stream, qh_h, kh_h, sc_s, scale, p);
      else        hipLaunchKernelGGL((attn_scores_k<16>), dim3(512), dim3(256), 0, stream, qh_h, kh_h, sc_s, scale, p);
    }
    hipLaunchKernelGGL(softmax_rows_k, dim3((24576+255)/256), dim3(256), 0, stream, sc_s, 24576, LK);
    for (int p=0;p<2;p++){
      GEMM(src, in_w + (long)(1024+p*256)*512, vh_h, in_b + 1024+p*256, nullptr,0, Mkv,  256,512, 512,512,256, 0);
      if (LK==48) hipLaunchKernelGGL((attn_av_k<48>), dim3(512), dim3(256), 0, stream, sc_s, vh_h, o_pv + p*256);
      else        hipLaunchKernelGGL((attn_av_k<16>), dim3(512), dim3(256), 0, stream, sc_s, vh_h, o_pv + p*256);
    }
    GEMM(o_pv, out_w, ca, out_b, nullptr,0, 24576,512,512, 512,512,512, 0);
    // fc contribution: logits (+)= ca @ fc_w[:, which*512 : ...]^T  (+ fc_b on first)
    GEMM(ca, fc_w + which*512, logits, which ? nullptr : fc_b, nullptr,0,
         24576,128,512, 512,1024,128, which);
  }

  // ---- entmax 1.5 + transpose to [B, SC, 128] ----
  hipLaunchKernelGGL(entmax_k, dim3(6144), dim3(256), 0, stream, logits, (float*)d_out);
}

// Round 4
// 9292.741 us; speedup vs baseline: 1.2197x; 1.2197x over previous
//
#include <hip/hip_runtime.h>
#include <math.h>

using bf16x8 = __attribute__((ext_vector_type(8))) short;
using f32x4  = __attribute__((ext_vector_type(4))) float;

__device__ __forceinline__ float sigf(float x){ return 1.f/(1.f+expf(-x)); }

__device__ __forceinline__ unsigned short f2bf(float x){
  union { float f; unsigned u; } v; v.f = x;
  unsigned r = v.u + 0x7FFF + ((v.u>>16)&1);
  return (unsigned short)(r>>16);
}
__device__ __forceinline__ float bf2f(unsigned short h){
  union { unsigned u; float f; } v; v.u = ((unsigned)h)<<16; return v.f;
}

// ---------------- zero fill ----------------
__global__ void zero_k(float* __restrict__ p, long n){
  long i = (long)blockIdx.x*blockDim.x + threadIdx.x;
  long stride = (long)gridDim.x*blockDim.x;
  for (; i<n; i+=stride) p[i] = 0.f;
}

// ---------------- fp32 -> bf16 ----------------
__global__ void cvt_k(const float* __restrict__ in, unsigned short* __restrict__ out, long n){
  long i = (long)blockIdx.x*blockDim.x + threadIdx.x;
  long stride = (long)gridDim.x*blockDim.x;
  for (; i<n; i+=stride) out[i] = f2bf(in[i]);
}

// ---------------- fp32 -> bf16 hi + lo (hi+lo ~= fp32 to 2^-17) ----------------
__global__ void split_k(const float* __restrict__ in, unsigned short* __restrict__ hi,
                        unsigned short* __restrict__ lo, long n){
  long i = (long)blockIdx.x*blockDim.x + threadIdx.x;
  long stride = (long)gridDim.x*blockDim.x;
  for (; i<n; i+=stride){
    float x = in[i];
    unsigned short h = f2bf(x);
    hi[i] = h;
    lo[i] = f2bf(x - bf2f(h));
  }
}

// ---------------- emb[b][d] = lang_embeds[ li[li[b]] ][d] ----------------
__global__ void emb_k(const int* __restrict__ li, const float* __restrict__ le, float* __restrict__ emb){
  int b = blockIdx.x, d = threadIdx.x;
  int idx = li[li[b]];
  emb[b*64+d] = le[idx*64+d];
}

// ---------------- out[b][s][0:D1]=seq, [D1:D1+D2]=emb[b]  (bf16 out) ----------------
__global__ void build_concat_k(const float* __restrict__ seq, const float* __restrict__ emb,
                               unsigned short* __restrict__ out, int S, int D1, int D2, long total){
  long i = (long)blockIdx.x*blockDim.x + threadIdx.x;
  if (i>=total) return;
  int D = D1+D2;
  int d = (int)(i % D);
  long bs = i / D;
  int s = (int)(bs % S);
  int b = (int)(bs / S);
  float v = (d<D1) ? seq[((long)b*S+s)*D1 + d] : emb[b*64 + (d-D1)];
  out[i] = f2bf(v);
}

// ------- split-bf16 MFMA GEMM: C[M,N] = (Ah+Al)[M,K] @ (Wh+Wl)[N,K]^T (+bias)
//         AS/BS = number of bf16 limbs per operand (1 or 2); 3-MFMA scheme drops lo*lo.
//         Output: Cf (fp32, optional accумulate) OR Chi/Clo (bf16 hi[/lo]).
//         M%128==0, N%128==0, K%32==0 -------
template<int AS, int BS>
__global__ __launch_bounds__(256) void gemm_ms_k(
    const unsigned short* __restrict__ Ah, const unsigned short* __restrict__ Al,
    const unsigned short* __restrict__ Wh, const unsigned short* __restrict__ Wl,
    float* __restrict__ Cf, unsigned short* __restrict__ Chi, unsigned short* __restrict__ Clo,
    const float* __restrict__ bias,
    int M, int N, int K, int lda, int ldb, int ldc, int accf)
{
  int bm = blockIdx.y*128, bn = blockIdx.x*128;
  int wid = threadIdx.x >> 6, lane = threadIdx.x & 63;
  int wr = (wid>>1)*64, wc = (wid&1)*64;
  int lrow = lane & 15;
  int lk   = (lane >> 4) * 8;
  long aoff = (long)(bm + wr + lrow)*lda + lk;
  long boff = (long)(bn + wc + lrow)*ldb + lk;
  f32x4 acc[4][4] = {};
  for (int k0=0; k0<K; k0+=32){
    bf16x8 ah[4], bh[4], al[4], bl[4];
    #pragma unroll
    for (int i=0;i<4;i++){
      ah[i] = *(const bf16x8*)(Ah + aoff + (long)(i*16)*lda + k0);
      bh[i] = *(const bf16x8*)(Wh + boff + (long)(i*16)*ldb + k0);
      if (AS==2) al[i] = *(const bf16x8*)(Al + aoff + (long)(i*16)*lda + k0);
      if (BS==2) bl[i] = *(const bf16x8*)(Wl + boff + (long)(i*16)*ldb + k0);
    }
    #pragma unroll
    for (int i=0;i<4;i++)
      #pragma unroll
      for (int j=0;j<4;j++){
        acc[i][j] = __builtin_amdgcn_mfma_f32_16x16x32_bf16(ah[i], bh[j], acc[i][j], 0,0,0);
        if (BS==2) acc[i][j] = __builtin_amdgcn_mfma_f32_16x16x32_bf16(ah[i], bl[j], acc[i][j], 0,0,0);
        if (AS==2) acc[i][j] = __builtin_amdgcn_mfma_f32_16x16x32_bf16(al[i], bh[j], acc[i][j], 0,0,0);
      }
  }
  int orow0 = bm + wr + (lane>>4)*4;
  int ocol0 = bn + wc + (lane&15);
  #pragma unroll
  for (int i=0;i<4;i++){
    #pragma unroll
    for (int j=0;j<4;j++){
      int col = ocol0 + j*16;
      float bv = bias ? bias[col] : 0.f;
      #pragma unroll
      for (int r=0;r<4;r++){
        int row = orow0 + i*16 + r;
        float v = acc[i][j][r] + bv;
        long idx = (long)row*ldc + col;
        if (Cf){
          if (accf) v += Cf[idx];
          Cf[idx] = v;
        } else {
          unsigned short h = f2bf(v);
          Chi[idx] = h;
          if (Clo) Clo[idx] = f2bf(v - bf2f(h));
        }
      }
    }
  }
}

// ------- fp32 GEMM (B transposed): C[M,N] = A[M,K] @ W[N,K]^T (+bias)(+=C) -------
__global__ __launch_bounds__(256) void gemm_bt_k(
    const float* __restrict__ A, const float* __restrict__ W, float* __restrict__ C,
    const float* __restrict__ bias, int M, int N, int K, int lda, int ldb, int ldc, int accflag)
{
  __shared__ float As[16][68];
  __shared__ float Ws[16][68];
  int bm = blockIdx.y*64, bn = blockIdx.x*64;
  int tid = threadIdx.x;
  int tr = tid>>4, tc = tid&15;
  float acc[4][4] = {};
  for (int k0=0;k0<K;k0+=16){
    #pragma unroll
    for (int i=0;i<4;i++){
      int idx = tid + i*256;
      int r = idx>>4, c = idx&15;
      float v = 0.f;
      if (bm+r<M && k0+c<K) v = A[(long)(bm+r)*lda + k0+c];
      As[c][r] = v;
    }
    #pragma unroll
    for (int i=0;i<4;i++){
      int idx = tid + i*256;
      int n = idx>>4, k = idx&15;
      float v = 0.f;
      if (bn+n<N && k0+k<K) v = W[(long)(bn+n)*ldb + k0+k];
      Ws[k][n] = v;
    }
    __syncthreads();
    #pragma unroll
    for (int kk=0;kk<16;kk++){
      float4 av = *(const float4*)&As[kk][tr*4];
      float4 bv = *(const float4*)&Ws[kk][tc*4];
      float a0[4] = {av.x, av.y, av.z, av.w};
      float b0[4] = {bv.x, bv.y, bv.z, bv.w};
      #pragma unroll
      for (int i=0;i<4;i++)
        #pragma unroll
        for (int j=0;j<4;j++)
          acc[i][j] += a0[i]*b0[j];
    }
    __syncthreads();
  }
  #pragma unroll
  for (int i=0;i<4;i++){
    int r = bm + tr*4 + i;
    if (r>=M) continue;
    #pragma unroll
    for (int j=0;j<4;j++){
      int n = bn + tc*4 + j;
      if (n>=N) continue;
      float v = acc[i][j];
      if (bias) v += bias[n];
      if (accflag) v += C[(long)r*ldc + n];
      C[(long)r*ldc + n] = v;
    }
  }
}

// ------- LSTM pointwise: gates g(+xg fp32) -> h,c fp32 states + bf16 hi[/lo] seq out -------
__global__ void lstm_act_k(const float* __restrict__ g, const float* __restrict__ xg, long ldxg,
                           float* __restrict__ c, float* __restrict__ h,
                           unsigned short* __restrict__ out_hi, unsigned short* __restrict__ out_lo,
                           int H, int ldstate, int outld){
  int j = blockIdx.x*blockDim.x + threadIdx.x;
  int b = blockIdx.y;
  if (j>=H) return;
  const float* gr = g + (long)b*4*H;
  float gi = gr[j], gf = gr[H+j], gg = gr[2*H+j], go = gr[3*H+j];
  if (xg){
    const float* xr = xg + (long)b*ldxg;
    gi += xr[j]; gf += xr[H+j]; gg += xr[2*H+j]; go += xr[3*H+j];
  }
  float cp = c[(long)b*ldstate + j];
  float cn = sigf(gf)*cp + sigf(gi)*tanhf(gg);
  float hn = sigf(go)*tanhf(cn);
  c[(long)b*ldstate + j] = cn;
  h[(long)b*ldstate + j] = hn;
  long oidx = (long)b*outld + j;
  if (out_hi){
    unsigned short hh = f2bf(hn);
    out_hi[oidx] = hh;
    if (out_lo) out_lo[oidx] = f2bf(hn - bf2f(hh));
  }
}

// ------- scores[b][q][k] = scale * dot(qh[q,b,:], kh[k,b,:]) over E=512, fp32 -------
template<int LK>
__global__ __launch_bounds__(256) void attn_scores_k(const float* __restrict__ qh,
                                                     const float* __restrict__ kh,
                                                     float* __restrict__ sc, float scale){
  __shared__ float Qs[48][65];
  __shared__ float Ks[LK][65];
  int b = blockIdx.x, tid = threadIdx.x;
  constexpr int NOUT = 48*LK;
  constexpr int NC = (NOUT + 255)/256;
  float acc[NC] = {};
  for (int e0=0;e0<512;e0+=64){
    for (int i=tid;i<48*64;i+=256){ int q=i>>6, e=i&63; Qs[q][e] = qh[((long)(q*512)+b)*512 + e0+e]; }
    for (int i=tid;i<LK*64;i+=256){ int k=i>>6, e=i&63; Ks[k][e] = kh[((long)(k*512)+b)*512 + e0+e]; }
    __syncthreads();
    #pragma unroll
    for (int c=0;c<NC;c++){
      int oi = tid + c*256;
      if (oi < NOUT){
        int q = oi / LK, k = oi % LK;
        float s = 0.f;
        #pragma unroll 8
        for (int e=0;e<64;e++) s += Qs[q][e]*Ks[k][e];
        acc[c] += s;
      }
    }
    __syncthreads();
  }
  #pragma unroll
  for (int c=0;c<NC;c++){
    int oi = tid + c*256;
    if (oi < NOUT){
      int q = oi / LK, k = oi % LK;
      sc[((long)b*48 + q)*LK + k] = acc[c]*scale;
    }
  }
}

// ---------------- row softmax (L small) ----------------
__global__ void softmax_rows_k(float* __restrict__ sc, int rows, int L){
  int r = blockIdx.x*blockDim.x + threadIdx.x;
  if (r>=rows) return;
  float* p = sc + (long)r*L;
  float m = -1e30f;
  for (int l=0;l<L;l++) m = fmaxf(m, p[l]);
  float s = 0.f;
  for (int l=0;l<L;l++){ float e = expf(p[l]-m); p[l]=e; s+=e; }
  float inv = 1.f/s;
  for (int l=0;l<L;l++) p[l]*=inv;
}

// ------- o[q][b][e] = sum_k attn[b][q][k]*vh[k][b][e]  (fp32 v, bf16 hi/lo out) -------
template<int LK>
__global__ __launch_bounds__(256) void attn_av_k(const float* __restrict__ at, const float* __restrict__ vh,
                                                 unsigned short* __restrict__ o_hi,
                                                 unsigned short* __restrict__ o_lo){
  __shared__ float As[48][LK+1];
  int b = blockIdx.x;
  int e = blockIdx.y*256 + threadIdx.x;
  for (int i=threadIdx.x;i<48*LK;i+=256){ int q=i/LK, k=i%LK; As[q][k] = at[((long)b*48+q)*LK + k]; }
  __syncthreads();
  float acc[48];
  #pragma unroll
  for (int q=0;q<48;q++) acc[q]=0.f;
  for (int k=0;k<LK;k++){
    float v = vh[((long)(k*512)+b)*512 + e];
    #pragma unroll
    for (int q=0;q<48;q++) acc[q] += As[q][k]*v;
  }
  #pragma unroll
  for (int q=0;q<48;q++){
    long idx = ((long)(q*512)+b)*512 + e;
    unsigned short hh = f2bf(acc[q]);
    o_hi[idx] = hh;
    o_lo[idx] = f2bf(acc[q] - bf2f(hh));
  }
}

// ------- exact 1.5-entmax via bisection; logits row (t,b) -> out[b][t][:] -------
__global__ void entmax_k(const float* __restrict__ logits, float* __restrict__ out){
  int wid = (blockIdx.x*blockDim.x + threadIdx.x)>>6;
  int lane = threadIdx.x & 63;
  if (wid >= 24576) return;
  const float* x = logits + (long)wid*128;
  float a = x[lane]*0.5f;
  float b2 = x[lane+64]*0.5f;
  float m = fmaxf(a,b2);
  #pragma unroll
  for (int off=32;off;off>>=1) m = fmaxf(m, __shfl_xor(m, off));
  a -= m; b2 -= m;
  float lo = -1.f, hi = 0.f;
  for (int it=0; it<32; ++it){
    float mid = 0.5f*(lo+hi);
    float va = fmaxf(a-mid,0.f), vb = fmaxf(b2-mid,0.f);
    float s = va*va + vb*vb;
    #pragma unroll
    for (int off=32;off;off>>=1) s += __shfl_xor(s, off);
    if (s >= 1.f) lo = mid; else hi = mid;
  }
  float tau = 0.5f*(lo+hi);
  int t = wid >> 9;
  int b = wid & 511;
  float* o = out + ((long)b*48 + t)*128;
  float va = fmaxf(a-tau,0.f), vb = fmaxf(b2-tau,0.f);
  o[lane] = va*va;
  o[lane+64] = vb*vb;
}

extern "C" void kernel_launch(void* const* d_in, const int* in_sizes, int n_in,
                              void* d_out, int out_size, void* d_ws, size_t ws_size,
                              hipStream_t stream) {
  const int*   li        = (const int*)  d_in[0];
  const float* char_seq  = (const float*)d_in[1];
  const float* tagset    = (const float*)d_in[2];
  const float* labels    = (const float*)d_in[3];
  const float* lang_emb  = (const float*)d_in[4];
  const float* c_wih_f   = (const float*)d_in[5];
  const float* c_whh_f   = (const float*)d_in[6];
  const float* c_b_f     = (const float*)d_in[7];
  const float* c_wih_b   = (const float*)d_in[8];
  const float* c_whh_b   = (const float*)d_in[9];
  const float* c_b_b     = (const float*)d_in[10];
  const float* t_wih_f   = (const float*)d_in[11];
  const float* t_whh_f   = (const float*)d_in[12];
  const float* t_b_f     = (const float*)d_in[13];
  const float* t_wih_b   = (const float*)d_in[14];
  const float* t_whh_b   = (const float*)d_in[15];
  const float* t_b_b     = (const float*)d_in[16];
  const float* cell_wih  = (const float*)d_in[17];
  const float* cell_whh  = (const float*)d_in[18];
  const float* cell_b    = (const float*)d_in[19];
  const float* c_in_w    = (const float*)d_in[20];
  const float* c_in_b    = (const float*)d_in[21];
  const float* c_out_w   = (const float*)d_in[22];
  const float* c_out_b   = (const float*)d_in[23];
  const float* t_in_w    = (const float*)d_in[24];
  const float* t_in_b    = (const float*)d_in[25];
  const float* t_out_w   = (const float*)d_in[26];
  const float* t_out_b   = (const float*)d_in[27];
  const float* fc_w      = (const float*)d_in[28];
  const float* fc_b      = (const float*)d_in[29];
  (void)n_in; (void)in_sizes; (void)out_size;

  float* w = (float*)d_ws;
  long off = 0;
  auto alloc = [&](long n){ float* p = w + off; off += n; return p; };
  auto alloc_us = [&](long n_us){ return (unsigned short*)alloc((n_us+1)/2); };

  float* emb    = alloc(32768);
  float* dec_h  = alloc(262144);
  float* dec_c  = alloc(262144);
  float* hb     = alloc(131072);
  float* cb     = alloc(131072);
  float* g      = alloc(1048576);
  float* logits = alloc(3145728);
  unsigned short* cwihf_hi = alloc_us(196608); unsigned short* cwihf_lo = alloc_us(196608);
  unsigned short* cwihb_hi = alloc_us(196608); unsigned short* cwihb_lo = alloc_us(196608);
  unsigned short* twihf_hi = alloc_us(131072); unsigned short* twihf_lo = alloc_us(131072);
  unsigned short* twihb_hi = alloc_us(131072); unsigned short* twihb_lo = alloc_us(131072);
  unsigned short* cellih_hi= alloc_us(262144); unsigned short* cellih_lo= alloc_us(262144);
  unsigned short* cinw_hi  = alloc_us(786432); unsigned short* cinw_lo  = alloc_us(786432);
  unsigned short* coutw_hi = alloc_us(262144); unsigned short* coutw_lo = alloc_us(262144);
  unsigned short* tinw_hi  = alloc_us(786432); unsigned short* tinw_lo  = alloc_us(786432);
  unsigned short* toutw_hi = alloc_us(262144); unsigned short* toutw_lo = alloc_us(262144);
  unsigned short* fcw_hi   = alloc_us(131072); unsigned short* fcw_lo   = alloc_us(131072);
  unsigned short* labels_bf= alloc_us(3145728);
  unsigned short* chout_hi = alloc_us(12582912);
  unsigned short* tgout_hi = alloc_us(4194304);
  unsigned short* hs_hi    = alloc_us(12582912);
  unsigned short* hs_lo    = alloc_us(12582912);
  float* arena = alloc(27525120);
  long needed_bytes = off * 4;
  if ((long)ws_size < needed_bytes) {
    hipLaunchKernelGGL(zero_k, dim3(64), dim3(256), 0, stream, (float*)d_out, (long)128);
    return;
  }

  // arena overlays (phases strictly sequential)
  unsigned short* cs_bf = (unsigned short*)arena;          // 4,718,592 us
  float* xg_c           = arena + 2359296;                 // 25,165,824 f (one direction)
  unsigned short* ts_bf = (unsigned short*)arena;          // 1,048,576 us
  float* xg_t           = arena + 524288;                  // 8,388,608 f
  float* qh   = arena;                                     // 12,582,912 f
  float* kh   = arena + 12582912;                          // 12,582,912 f
  float* vh   = qh;                                        // after scores
  unsigned short* opv_hi = (unsigned short*)kh;            // after scores (kh dead)
  unsigned short* opv_lo = (unsigned short*)(arena + 12582912 + 6291456);
  unsigned short* ca_hi  = (unsigned short*)qh;            // after attn_av (vh dead)
  unsigned short* ca_lo  = (unsigned short*)(arena + 6291456);
  float* sc_s = arena + 25165824;                          // 1,179,648 f

  auto GEMM = [&](const float* A, const float* W2, float* C, const float* bias,
                  int M,int N,int K,int lda,int ldb,int ldc,int accf){
    dim3 gr((N+63)/64, (M+63)/64);
    hipLaunchKernelGGL(gemm_bt_k, gr, dim3(256), 0, stream, A,W2,C,bias,M,N,K,lda,ldb,ldc,accf);
  };
  auto MS = [&](int AS, const unsigned short* Ah, const unsigned short* Al,
                const unsigned short* Wh, const unsigned short* Wl,
                float* Cf, unsigned short* Chi, unsigned short* Clo, const float* bias,
                int M,int N,int K,int lda,int ldb,int ldc,int accf){
    dim3 gr(N/128, M/128);
    if (AS==1) hipLaunchKernelGGL((gemm_ms_k<1,2>), gr, dim3(256), 0, stream,
                                  Ah,Al,Wh,Wl,Cf,Chi,Clo,bias,M,N,K,lda,ldb,ldc,accf);
    else       hipLaunchKernelGGL((gemm_ms_k<2,2>), gr, dim3(256), 0, stream,
                                  Ah,Al,Wh,Wl,Cf,Chi,Clo,bias,M,N,K,lda,ldb,ldc,accf);
  };
  auto SPLIT = [&](const float* src, unsigned short* hi, unsigned short* lo, long n){
    hipLaunchKernelGGL(split_k, dim3(256), dim3(256), 0, stream, src, hi, lo, n);
  };

  // ---- weight splits + labels bf16 ----
  SPLIT(c_wih_f, cwihf_hi, cwihf_lo, 196608);
  SPLIT(c_wih_b, cwihb_hi, cwihb_lo, 196608);
  SPLIT(t_wih_f, twihf_hi, twihf_lo, 131072);
  SPLIT(t_wih_b, twihb_hi, twihb_lo, 131072);
  SPLIT(cell_wih, cellih_hi, cellih_lo, 262144);
  SPLIT(c_in_w,  cinw_hi,  cinw_lo,  786432);
  SPLIT(c_out_w, coutw_hi, coutw_lo, 262144);
  SPLIT(t_in_w,  tinw_hi,  tinw_lo,  786432);
  SPLIT(t_out_w, toutw_hi, toutw_lo, 262144);
  SPLIT(fc_w,    fcw_hi,   fcw_lo,   131072);
  hipLaunchKernelGGL(cvt_k, dim3(256), dim3(256), 0, stream, labels, labels_bf, (long)3145728);

  // ---- emb + zero states ----
  hipLaunchKernelGGL(emb_k, dim3(512), dim3(64), 0, stream, li, lang_emb, emb);
  hipLaunchKernelGGL(zero_k, dim3(512), dim3(256), 0, stream, dec_h, (long)786432);

  // ---- char phase ----
  {
    long tot = 512l*48*192;
    hipLaunchKernelGGL(build_concat_k, dim3((unsigned)((tot+255)/256)), dim3(256), 0, stream,
                       char_seq, emb, cs_bf, 48, 128, 64, tot);
  }
  MS(1, cs_bf, nullptr, cwihf_hi, cwihf_lo, xg_c, nullptr, nullptr, c_b_f,
     24576,1024,192, 192,192,1024, 0);
  for (int t=0;t<48;t++){
    GEMM(dec_h, c_whh_f, g, nullptr, 512,1024,256, 512,256,1024, 0);
    hipLaunchKernelGGL(lstm_act_k, dim3(1,512), dim3(256), 0, stream,
                       g, xg_c + (long)t*1024, (long)48*1024, dec_c, dec_h,
                       chout_hi + (long)t*262144, (unsigned short*)nullptr, 256, 512, 512);
  }
  MS(1, cs_bf, nullptr, cwihb_hi, cwihb_lo, xg_c, nullptr, nullptr, c_b_b,
     24576,1024,192, 192,192,1024, 0);
  for (int t=0;t<48;t++){
    GEMM(hb, c_whh_b, g, nullptr, 512,1024,256, 256,256,1024, 0);
    hipLaunchKernelGGL(lstm_act_k, dim3(1,512), dim3(256), 0, stream,
                       g, xg_c + (long)(47-t)*1024, (long)48*1024, cb, hb,
                       chout_hi + (long)(47-t)*262144 + 256, (unsigned short*)nullptr, 256, 256, 512);
  }

  // ---- tag phase ----
  {
    long tot = 512l*16*128;
    hipLaunchKernelGGL(build_concat_k, dim3((unsigned)((tot+255)/256)), dim3(256), 0, stream,
                       tagset, emb, ts_bf, 16, 64, 64, tot);
  }
  MS(1, ts_bf, nullptr, twihf_hi, twihf_lo, xg_t, nullptr, nullptr, t_b_f,
     8192,1024,128, 128,128,1024, 0);
  for (int t=0;t<16;t++){
    GEMM(dec_h+256, t_whh_f, g, nullptr, 512,1024,256, 512,256,1024, 0);
    hipLaunchKernelGGL(lstm_act_k, dim3(1,512), dim3(256), 0, stream,
                       g, xg_t + (long)t*1024, (long)16*1024, dec_c+256, dec_h+256,
                       tgout_hi + (long)t*262144, (unsigned short*)nullptr, 256, 512, 512);
  }
  hipLaunchKernelGGL(zero_k, dim3(256), dim3(256), 0, stream, hb, (long)262144);
  MS(1, ts_bf, nullptr, twihb_hi, twihb_lo, xg_t, nullptr, nullptr, t_b_b,
     8192,1024,128, 128,128,1024, 0);
  for (int t=0;t<16;t++){
    GEMM(hb, t_whh_b, g, nullptr, 512,1024,256, 256,256,1024, 0);
    hipLaunchKernelGGL(lstm_act_k, dim3(1,512), dim3(256), 0, stream,
                       g, xg_t + (long)(15-t)*1024, (long)16*1024, cb, hb,
                       tgout_hi + (long)(15-t)*262144 + 256, (unsigned short*)nullptr, 256, 256, 512);
  }

  // ---- decoder ----
  for (int t=0;t<48;t++){
    if (t==0){
      GEMM(dec_h, cell_whh, g, cell_b, 512,2048,512, 512,512,2048, 0);
    } else {
      MS(1, labels_bf + (long)t*128, nullptr, cellih_hi, cellih_lo, g, nullptr, nullptr, cell_b,
         512,2048,128, 48*128,128,2048, 0);
      GEMM(dec_h, cell_whh, g, nullptr, 512,2048,512, 512,512,2048, 1);
    }
    hipLaunchKernelGGL(lstm_act_k, dim3(2,512), dim3(256), 0, stream,
                       g, (const float*)nullptr, (long)0, dec_c, dec_h,
                       hs_hi + (long)t*262144, hs_lo + (long)t*262144, 512, 512, 512);
  }

  const float scale = 0.044194173824159216f; // 1/sqrt(512)

  // ---- attentions ----
  for (int which=0; which<2; ++which){
    const float* in_b  = which ? t_in_b  : c_in_b;
    const float* out_b = which ? t_out_b : c_out_b;
    const unsigned short* inw_hi = which ? tinw_hi : cinw_hi;
    const unsigned short* inw_lo = which ? tinw_lo : cinw_lo;
    const unsigned short* outw_hi= which ? toutw_hi: coutw_hi;
    const unsigned short* outw_lo= which ? toutw_lo: coutw_lo;
    const unsigned short* src    = which ? tgout_hi: chout_hi;
    int Mkv = which ? 8192 : 24576;
    int LK  = which ? 16 : 48;
    // q: A = hs hi/lo (split), W = Wq hi/lo -> fp32 qh
    MS(2, hs_hi, hs_lo, inw_hi, inw_lo, qh, nullptr, nullptr, in_b,
       24576,512,512, 512,512,512, 0);
    // k: A = encoder h (bf16 hi), W hi/lo -> fp32 kh
    MS(1, src, nullptr, inw_hi + (long)512*512, inw_lo + (long)512*512, kh, nullptr, nullptr, in_b+512,
       Mkv,512,512, 512,512,512, 0);
    if (LK==48) hipLaunchKernelGGL((attn_scores_k<48>), dim3(512), dim3(256), 0, stream, qh, kh, sc_s, scale);
    else        hipLaunchKernelGGL((attn_scores_k<16>), dim3(512), dim3(256), 0, stream, qh, kh, sc_s, scale);
    hipLaunchKernelGGL(softmax_rows_k, dim3((24576+255)/256), dim3(256), 0, stream, sc_s, 24576, LK);
    // v: fp32 vh (into qh slot; qh dead after scores)
    MS(1, src, nullptr, inw_hi + (long)1024*512, inw_lo + (long)1024*512, vh, nullptr, nullptr, in_b+1024,
       Mkv,512,512, 512,512,512, 0);
    // opv = attn @ v -> hi/lo (into kh slot)
    if (LK==48) hipLaunchKernelGGL((attn_av_k<48>), dim3(512,2), dim3(256), 0, stream, sc_s, vh, opv_hi, opv_lo);
    else        hipLaunchKernelGGL((attn_av_k<16>), dim3(512,2), dim3(256), 0, stream, sc_s, vh, opv_hi, opv_lo);
    // ca = opv @ Wout^T -> hi/lo (into qh slot; vh dead)
    MS(2, opv_hi, opv_lo, outw_hi, outw_lo, nullptr, ca_hi, ca_lo, out_b,
       24576,512,512, 512,512,512, 0);
    // logits (+)= ca @ fc_w[:, which*512:+512]^T (+ fc_b on first)
    MS(2, ca_hi, ca_lo, fcw_hi + which*512, fcw_lo + which*512, logits, nullptr, nullptr,
       which ? nullptr : fc_b, 24576,128,512, 512,1024,128, which);
  }

  // ---- entmax 1.5 + transpose to [B, SC, 128] ----
  hipLaunchKernelGGL(entmax_k, dim3(6144), dim3(256), 0, stream, logits, (float*)d_out);
}